// Round 2
// baseline (294.086 us; speedup 1.0000x reference)
//
#include <hip/hip_runtime.h>
#include <hip/hip_bf16.h>

#define NODES 2048
#define DIM   64
#define K_TOP 30
#define BATCH 16
#define BN    (NODES * BATCH)
#define NEGINF (-3.402823466e38f)
#define EPS 1e-5f

// ---------------------------------------------------------------------------
// K1: row norms of embedding  (one wave per row)
// ---------------------------------------------------------------------------
__global__ __launch_bounds__(256) void norms_kernel(const float* __restrict__ w,
                                                    float* __restrict__ nrm) {
    int r = blockIdx.x * 4 + (threadIdx.x >> 6);
    int lane = threadIdx.x & 63;
    float v = w[r * DIM + lane];
    float s = v * v;
    #pragma unroll
    for (int off = 32; off; off >>= 1) s += __shfl_xor(s, off, 64);
    if (lane == 0) nrm[r] = sqrtf(s);
}

// ---------------------------------------------------------------------------
// K2: cosine-similarity row + iterative top-30 argmax (one block per row)
// tie-break: lower index wins (matches jax.lax.top_k ordering semantics)
// ---------------------------------------------------------------------------
__global__ __launch_bounds__(256) void cos_topk_kernel(const float* __restrict__ w,
                                                       const float* __restrict__ nrm,
                                                       int* __restrict__ topk) {
    const int i = blockIdx.x;
    const int tid = threadIdx.x;
    __shared__ float wi[DIM];
    __shared__ float row[NODES];
    __shared__ float rbv[4];
    __shared__ int   rbi[4];

    if (tid < DIM) wi[tid] = w[i * DIM + tid];
    __syncthreads();

    const float ni = nrm[i];
    for (int j = tid; j < NODES; j += 256) {
        const float4* wj = (const float4*)(w + j * DIM);
        float acc = 0.f;
        #pragma unroll
        for (int q = 0; q < DIM / 4; ++q) {
            float4 v = wj[q];
            acc = fmaf(v.x, wi[q * 4 + 0], acc);
            acc = fmaf(v.y, wi[q * 4 + 1], acc);
            acc = fmaf(v.z, wi[q * 4 + 2], acc);
            acc = fmaf(v.w, wi[q * 4 + 3], acc);
        }
        row[j] = acc / (ni * nrm[j]);
    }
    __syncthreads();

    const int lane = tid & 63;
    const int wv = tid >> 6;
    for (int t = 0; t < K_TOP; ++t) {
        float bv = NEGINF;
        int bi = -1;
        for (int j = tid; j < NODES; j += 256) {
            float v = row[j];
            if (v > bv) { bv = v; bi = j; }   // ascending j -> lowest idx on tie
        }
        // wave argmax reduce (lower index wins on exact tie)
        #pragma unroll
        for (int off = 32; off; off >>= 1) {
            float ov = __shfl_down(bv, off, 64);
            int   oi = __shfl_down(bi, off, 64);
            if (ov > bv || (ov == bv && (unsigned)oi < (unsigned)bi)) { bv = ov; bi = oi; }
        }
        if (lane == 0) { rbv[wv] = bv; rbi[wv] = bi; }
        __syncthreads();
        if (tid == 0) {
            float v = rbv[0]; int ix = rbi[0];
            #pragma unroll
            for (int q = 1; q < 4; ++q)
                if (rbv[q] > v || (rbv[q] == v && (unsigned)rbi[q] < (unsigned)ix)) { v = rbv[q]; ix = rbi[q]; }
            topk[i * K_TOP + t] = ix;
            row[ix] = NEGINF;
        }
        __syncthreads();
    }
}

// ---------------------------------------------------------------------------
// K3: xl = x @ lin_w ; a_i/a_j per node (fused). One wave per output row.
// ---------------------------------------------------------------------------
__global__ __launch_bounds__(256) void lin_kernel(const float* __restrict__ x,
                                                  const float* __restrict__ lin_w,
                                                  const float* __restrict__ emb,
                                                  const float* __restrict__ att_i,
                                                  const float* __restrict__ att_j,
                                                  const float* __restrict__ att_em_i,
                                                  const float* __restrict__ att_em_j,
                                                  float* __restrict__ xl,
                                                  float* __restrict__ ai,
                                                  float* __restrict__ aj) {
    __shared__ float lw[DIM * DIM];   // 16 KiB
    __shared__ float xs[16 * DIM];    // 4 KiB
    const int tid = threadIdx.x;
    const int wave = tid >> 6;
    const int lane = tid & 63;
    const int row0 = blockIdx.x * 16;

    for (int t = tid; t < DIM * DIM; t += 256) lw[t] = lin_w[t];
    for (int t = tid; t < 16 * DIM; t += 256) xs[t] = x[row0 * DIM + t];
    __syncthreads();

    for (int rr = wave; rr < 16; rr += 4) {
        const int r = row0 + rr;
        float acc = 0.f;
        #pragma unroll
        for (int f = 0; f < DIM; ++f)
            acc = fmaf(xs[rr * DIM + f], lw[f * DIM + lane], acc);  // lane stride-64: 2/bank = free
        xl[r * DIM + lane] = acc;

        const int i = r & (NODES - 1);
        const float em = emb[i * DIM + lane];
        float ti = acc * att_i[lane] + em * att_em_i[lane];
        float tj = acc * att_j[lane] + em * att_em_j[lane];
        #pragma unroll
        for (int off = 32; off; off >>= 1) {
            ti += __shfl_xor(ti, off, 64);
            tj += __shfl_xor(tj, off, 64);
        }
        if (lane == 0) { ai[r] = ti; aj[r] = tj; }
    }
}

// ---------------------------------------------------------------------------
// K4: per-node fused GAT aggregate + BN1 + ReLU + emb-mul + BN2 + ReLU + readout
// one 64-lane wave per target node; lane == feature dim
// ---------------------------------------------------------------------------
__global__ __launch_bounds__(256) void agg_kernel(const int* __restrict__ topk,
                                                  const float* __restrict__ xl,
                                                  const float* __restrict__ ai,
                                                  const float* __restrict__ aj,
                                                  const float* __restrict__ emb,
                                                  const float* __restrict__ gnn_bias,
                                                  const float* __restrict__ g1, const float* __restrict__ b1,
                                                  const float* __restrict__ m1, const float* __restrict__ v1,
                                                  const float* __restrict__ g2, const float* __restrict__ b2,
                                                  const float* __restrict__ m2, const float* __restrict__ v2,
                                                  const float* __restrict__ out_w,
                                                  const float* __restrict__ out_b,
                                                  float* __restrict__ y) {
    const int e = blockIdx.x * 4 + (threadIdx.x >> 6);
    const int lane = threadIdx.x & 63;
    const int i = e & (NODES - 1);
    const int b = e >> 11;

    const float a_ie = ai[e];
    int nbr = 0;
    float raw = NEGINF;
    if (lane < K_TOP) {
        nbr = (b << 11) + topk[i * K_TOP + lane];
        float r0 = a_ie + aj[nbr];
        raw = (r0 >= 0.f) ? r0 : 0.2f * r0;   // leaky_relu(0.2)
    }
    float m = raw;
    #pragma unroll
    for (int off = 32; off; off >>= 1) m = fmaxf(m, __shfl_xor(m, off, 64));
    float p = (lane < K_TOP) ? __expf(raw - m) : 0.f;
    float s = p;
    #pragma unroll
    for (int off = 32; off; off >>= 1) s += __shfl_xor(s, off, 64);
    const float inv = 1.f / s;

    float acc = 0.f;
    #pragma unroll
    for (int k = 0; k < K_TOP; ++k) {
        const float pk = __shfl(p, k, 64);
        const int nb = __shfl(nbr, k, 64);
        acc = fmaf(pk, xl[nb * DIM + lane], acc);  // 256B coalesced gather, L2-resident
    }

    float o = acc * inv + gnn_bias[lane];
    o = (o - m1[lane]) * rsqrtf(v1[lane] + EPS) * g1[lane] + b1[lane];
    o = fmaxf(o, 0.f);
    float h = o * emb[i * DIM + lane];
    h = (h - m2[lane]) * rsqrtf(v2[lane] + EPS) * g2[lane] + b2[lane];
    h = fmaxf(h, 0.f);
    float t = h * out_w[lane];
    #pragma unroll
    for (int off = 32; off; off >>= 1) t += __shfl_xor(t, off, 64);
    if (lane == 0) y[e] = t + out_b[0];
}

// ---------------------------------------------------------------------------
extern "C" void kernel_launch(void* const* d_in, const int* in_sizes, int n_in,
                              void* d_out, int out_size, void* d_ws, size_t ws_size,
                              hipStream_t stream) {
    const float* data      = (const float*)d_in[0];
    // d_in[1] org_edge_index: unused (prior_graph dynamic top-k path)
    const float* emb       = (const float*)d_in[2];
    const float* lin_w     = (const float*)d_in[3];
    const float* att_i     = (const float*)d_in[4];
    const float* att_j     = (const float*)d_in[5];
    const float* att_em_i  = (const float*)d_in[6];
    const float* att_em_j  = (const float*)d_in[7];
    const float* gnn_bias  = (const float*)d_in[8];
    const float* bn1_gamma = (const float*)d_in[9];
    const float* bn1_beta  = (const float*)d_in[10];
    const float* bn1_mean  = (const float*)d_in[11];
    const float* bn1_var   = (const float*)d_in[12];
    const float* bn2_gamma = (const float*)d_in[13];
    const float* bn2_beta  = (const float*)d_in[14];
    const float* bn2_mean  = (const float*)d_in[15];
    const float* bn2_var   = (const float*)d_in[16];
    const float* out_w     = (const float*)d_in[17];
    const float* out_b     = (const float*)d_in[18];
    float* y = (float*)d_out;

    // workspace layout (bytes)
    char* ws = (char*)d_ws;
    float* nrm  = (float*)(ws + 0);                    //  2048 f32
    int*   topk = (int*)(ws + 8192);                   //  2048*30 i32
    float* xl   = (float*)(ws + 262144);               //  32768*64 f32 (8 MiB)
    float* ai   = (float*)(ws + 262144 + 8388608);     //  32768 f32
    float* aj   = (float*)(ws + 262144 + 8388608 + 131072);

    norms_kernel<<<NODES / 4, 256, 0, stream>>>(emb, nrm);
    cos_topk_kernel<<<NODES, 256, 0, stream>>>(emb, nrm, topk);
    lin_kernel<<<BN / 16, 256, 0, stream>>>(data, lin_w, emb, att_i, att_j,
                                            att_em_i, att_em_j, xl, ai, aj);
    agg_kernel<<<BN / 4, 256, 0, stream>>>(topk, xl, ai, aj, emb, gnn_bias,
                                           bn1_gamma, bn1_beta, bn1_mean, bn1_var,
                                           bn2_gamma, bn2_beta, bn2_mean, bn2_var,
                                           out_w, out_b, y);
}